// Round 4
// baseline (328.503 us; speedup 1.0000x reference)
//
#include <hip/hip_runtime.h>
#include <hip/hip_bf16.h>

// Problem: B=32, c_in=32, T=12, N=1024, ks=3, c_out=64
//   x_c[b,i,t,k,n] = sum_m Lk[k,n,m] * x[b,i,t,m]       (GEMM: 12288 x 3072 x 1024)
//   x_gc[b,o,t,n]  = sum_{i,k} theta[i,o,k]*x_c + b[o]
//   out = relu(x_gc + pad(x))
//
// R3: GEMM epilogue now stages C-tile in LDS (reusing staging buffers) and
//     stores coalesced 16B/thread. Was 64 scalar 2B stores/thread.

typedef __attribute__((ext_vector_type(8))) short s16x8;
typedef __attribute__((ext_vector_type(4))) float f32x4;
typedef __attribute__((ext_vector_type(4))) float fvec4;

__device__ __forceinline__ short f2bf(float f) {
    union { float f; unsigned u; } v; v.f = f;
    unsigned r = v.u + 0x7fffu + ((v.u >> 16) & 1u);   // RNE
    return (short)(r >> 16);
}
__device__ __forceinline__ float bf2f(short h) {
    union { unsigned u; float f; } v; v.u = ((unsigned)(unsigned short)h) << 16;
    return v.f;
}

// ---- fp32 -> bf16 convert, 8 elems/thread -------------------------------
__global__ __launch_bounds__(256) void cvt_bf16_k(const float* __restrict__ src,
                                                  short* __restrict__ dst, int n8) {
    int i = blockIdx.x * 256 + threadIdx.x;
    if (i >= n8) return;
    const fvec4* s4 = (const fvec4*)src;
    fvec4 a = s4[2 * i], b = s4[2 * i + 1];
    s16x8 o;
    o[0] = f2bf(a[0]); o[1] = f2bf(a[1]); o[2] = f2bf(a[2]); o[3] = f2bf(a[3]);
    o[4] = f2bf(b[0]); o[5] = f2bf(b[1]); o[6] = f2bf(b[2]); o[7] = f2bf(b[3]);
    ((s16x8*)dst)[i] = o;
}

// ---- theta (i,o,k) -> thT2[(i*3+k)*64 + o] ------------------------------
__global__ __launch_bounds__(256) void tth_k(const float* __restrict__ th,
                                             float* __restrict__ thT) {
    int idx = blockIdx.x * 256 + threadIdx.x;
    if (idx >= 6144) return;
    int i = idx / 192, rem = idx % 192;
    int o = rem / 3, k = rem % 3;
    thT[(i * 3 + k) * 64 + o] = th[idx];
}

// ---- bf16 MFMA GEMM, C = A * B^T; A:12288x1024, Bm(row n', col m):3072x1024
// 128x128 tile, BK=64, 4 waves (2x2), 16x16x32 MFMA, global_load_lds w=16.
__global__ __launch_bounds__(256) void gemm_bt_k(const short* __restrict__ A,
                                                 const short* __restrict__ Bm,
                                                 short* __restrict__ C) {
    __shared__ short smem[16384];        // lA = smem[0..8191], lB = smem[8192..]
    short* lA = smem;
    short* lB = smem + 8192;
    const int tid = threadIdx.x;
    const int lane = tid & 63;
    const int w = tid >> 6;
    const int wm = w >> 1, wn = w & 1;
    const int bn = blockIdx.x, bm = blockIdx.y;
    const int arow0 = bm * 128, brow0 = bn * 128;
    const int s_row = lane >> 3;          // 0..7 row within 8-row group
    const int s_col = (lane & 7) * 8;     // bf16 col offset

    f32x4 acc[4][4] = {};

    for (int kt = 0; kt < 16; ++kt) {
        const int k0 = kt * 64;
        #pragma unroll
        for (int j = 0; j < 4; ++j) {
            const int g = w * 4 + j;      // 8-row group id, wave-uniform
            __builtin_amdgcn_global_load_lds(
                (const __attribute__((address_space(1))) void*)
                    (A + (arow0 + g * 8 + s_row) * 1024 + k0 + s_col),
                (__attribute__((address_space(3))) void*)(&lA[g * 512]), 16, 0, 0);
            __builtin_amdgcn_global_load_lds(
                (const __attribute__((address_space(1))) void*)
                    (Bm + (brow0 + g * 8 + s_row) * 1024 + k0 + s_col),
                (__attribute__((address_space(3))) void*)(&lB[g * 512]), 16, 0, 0);
        }
        __syncthreads();
        #pragma unroll
        for (int ks = 0; ks < 2; ++ks) {
            const int kf = ks * 32 + (lane >> 4) * 8;
            s16x8 af[4], bfr[4];
            #pragma unroll
            for (int mi = 0; mi < 4; ++mi)
                af[mi] = *(const s16x8*)&lA[(wm * 64 + mi * 16 + (lane & 15)) * 64 + kf];
            #pragma unroll
            for (int ni = 0; ni < 4; ++ni)
                bfr[ni] = *(const s16x8*)&lB[(wn * 64 + ni * 16 + (lane & 15)) * 64 + kf];
            #pragma unroll
            for (int mi = 0; mi < 4; ++mi)
                #pragma unroll
                for (int ni = 0; ni < 4; ++ni)
                    acc[mi][ni] = __builtin_amdgcn_mfma_f32_16x16x32_bf16(
                        af[mi], bfr[ni], acc[mi][ni], 0, 0, 0);
        }
        __syncthreads();
    }

    // ---- epilogue: stage C-tile (128x128 bf16 = 32 KB) in smem, then
    //      coalesced 16B stores. C/D frag layout: col=lane&15,
    //      row=(lane>>4)*4+reg (HW-verified m89/m91).
    const int rq = (lane >> 4) * 4;
    const int cc = lane & 15;
    #pragma unroll
    for (int mi = 0; mi < 4; ++mi) {
        #pragma unroll
        for (int ni = 0; ni < 4; ++ni) {
            const int Lr = wm * 64 + mi * 16 + rq;
            const int Lc = wn * 64 + ni * 16 + cc;
            #pragma unroll
            for (int r = 0; r < 4; ++r)
                smem[(Lr + r) * 128 + Lc] = f2bf(acc[mi][ni][r]);
        }
    }
    __syncthreads();
    const int prow = tid >> 4;            // 0..15
    const int pcol = (tid & 15) * 8;      // 0..120, 16B-aligned
    #pragma unroll
    for (int p = 0; p < 8; ++p) {
        const int Lr = p * 16 + prow;
        s16x8 v = *(const s16x8*)&smem[Lr * 128 + pcol];
        *(s16x8*)&C[(arow0 + Lr) * 3072 + brow0 + pcol] = v;
    }
}

// ---- stage 2: theta contraction + bias + residual pad + relu ------------
// xc: (b,i,t, k*1024+n) bf16; thT2: [ik=96][o=64] f32; out: (b,o,t,n) f32
// Accumulator-major structure: per-thread acc[64] (registers, static idx),
// stream over ik. theta rows are wave-uniform -> scalar loads.
__global__ __launch_bounds__(256) void stage2_k(const short* __restrict__ xc,
                                                const float* __restrict__ thT,
                                                const float* __restrict__ bias,
                                                const float* __restrict__ x,
                                                float* __restrict__ out) {
    const int blk = blockIdx.x;
    const int tid = threadIdx.x;
    const int nb = blk & 3;
    const int bt = blk >> 2;          // b*12 + t
    const int b  = bt / 12;
    const int t  = bt - b * 12;
    const int n  = nb * 256 + tid;

    float acc[64];
    #pragma unroll
    for (int o = 0; o < 64; ++o) acc[o] = 0.f;

    const int xcbase = (b * 384 + t) * 3072 + n;   // i = 0, k = 0
    for (int i = 0; i < 32; ++i) {
        const int base = xcbase + i * 36864;
        const float v0 = bf2f(xc[base]);
        const float v1 = bf2f(xc[base + 1024]);
        const float v2 = bf2f(xc[base + 2048]);
        const float* t0 = thT + (i * 3) * 64;      // wave-uniform
        #pragma unroll
        for (int o = 0; o < 64; ++o)
            acc[o] = fmaf(t0[o], v0,
                     fmaf(t0[64 + o], v1,
                     fmaf(t0[128 + o], v2, acc[o])));
    }

    const int xrbase = (b * 384 + t) * 1024 + n;   // residual, i = o
    const int obase  = (b * 768 + t) * 1024 + n;
    #pragma unroll
    for (int o = 0; o < 64; ++o) {
        float s = acc[o] + bias[o];
        if (o < 32) s += x[xrbase + o * 12288];
        out[obase + o * 12288] = fmaxf(s, 0.f);
    }
}

extern "C" void kernel_launch(void* const* d_in, const int* in_sizes, int n_in,
                              void* d_out, int out_size, void* d_ws, size_t ws_size,
                              hipStream_t stream) {
    const float* x     = (const float*)d_in[0];
    const float* Lk    = (const float*)d_in[1];
    const float* theta = (const float*)d_in[2];
    const float* bias  = (const float*)d_in[3];
    float* out = (float*)d_out;

    char* ws = (char*)d_ws;
    short* xb  = (short*)(ws);                                  // 25,165,824 B
    short* lb  = (short*)(ws + 25165824);                       //  6,291,456 B
    float* thT = (float*)(ws + 25165824 + 6291456);             //     24,576 B
    short* xc  = (short*)(ws + 25165824 + 6291456 + 24576);     // 75,497,472 B
    // total ws need: 106,979,328 B

    hipLaunchKernelGGL(cvt_bf16_k, dim3(6144), dim3(256), 0, stream, x,  xb, 1572864);
    hipLaunchKernelGGL(cvt_bf16_k, dim3(1536), dim3(256), 0, stream, Lk, lb, 393216);
    hipLaunchKernelGGL(tth_k,      dim3(24),   dim3(256), 0, stream, theta, thT);
    hipLaunchKernelGGL(gemm_bt_k,  dim3(24, 96), dim3(256), 0, stream, xb, lb, xc);
    hipLaunchKernelGGL(stage2_k,   dim3(1536), dim3(256), 0, stream, xc, thT, bias, x, out);
}

// Round 5
// 305.590 us; speedup vs baseline: 1.0750x; 1.0750x over previous
//
#include <hip/hip_runtime.h>
#include <hip/hip_bf16.h>

// Problem: B=32, c_in=32, T=12, N=1024, ks=3, c_out=64
//   x_c = Lk-GEMM: C[12288 x 3072] = A[12288 x 1024] * Bm[3072 x 1024]^T (bf16)
//   stage2: out[b,o,t,n] = relu(sum_ik thT[ik][o]*xc + bias + pad(x))
//
// R5: GEMM ported to the 256^2 8-phase template (T1+T2+T3+T4+T5).
//     BK=64, 512 thr (2x4 waves), 128KiB LDS, counted vmcnt(4) at K-tile
//     boundaries only, XOR-swizzle ((row&7)<<4) both-sides, setprio(1)
//     around 16-MFMA clusters.

typedef __attribute__((ext_vector_type(8))) short s16x8;
typedef __attribute__((ext_vector_type(4))) float f32x4;
typedef __attribute__((ext_vector_type(4))) float fvec4;

__device__ __forceinline__ short f2bf(float f) {
    union { float f; unsigned u; } v; v.f = f;
    unsigned r = v.u + 0x7fffu + ((v.u >> 16) & 1u);   // RNE
    return (short)(r >> 16);
}
__device__ __forceinline__ float bf2f(short h) {
    union { unsigned u; float f; } v; v.u = ((unsigned)(unsigned short)h) << 16;
    return v.f;
}

// ---- fp32 -> bf16 convert, 8 elems/thread -------------------------------
__global__ __launch_bounds__(256) void cvt_bf16_k(const float* __restrict__ src,
                                                  short* __restrict__ dst, int n8) {
    int i = blockIdx.x * 256 + threadIdx.x;
    if (i >= n8) return;
    const fvec4* s4 = (const fvec4*)src;
    fvec4 a = s4[2 * i], b = s4[2 * i + 1];
    s16x8 o;
    o[0] = f2bf(a[0]); o[1] = f2bf(a[1]); o[2] = f2bf(a[2]); o[3] = f2bf(a[3]);
    o[4] = f2bf(b[0]); o[5] = f2bf(b[1]); o[6] = f2bf(b[2]); o[7] = f2bf(b[3]);
    ((s16x8*)dst)[i] = o;
}

// ---- theta (i,o,k) -> thT2[(i*3+k)*64 + o] ------------------------------
__global__ __launch_bounds__(256) void tth_k(const float* __restrict__ th,
                                             float* __restrict__ thT) {
    int idx = blockIdx.x * 256 + threadIdx.x;
    if (idx >= 6144) return;
    int i = idx / 192, rem = idx % 192;
    int o = rem / 3, k = rem % 3;
    thT[(i * 3 + k) * 64 + o] = th[idx];
}

// ===== 8-phase 256x256 GEMM =============================================
// A slot(buf,h) @ shorts (buf*2+h)*8192 ; B slot @ 32768 + (buf*2+h)*8192.
// Half-tile = 128 rows x 64 k, row-major [128][64], stride 128B.
// T2 swizzle: phys_colbyte = log_colbyte ^ ((row&7)<<4), involution,
// applied via pre-swizzled GLOBAL source (stage) + swizzled ds_read.
#define STAGE(ptr, rowbase, tt, hh, slotbase)                                   \
    {                                                                           \
        _Pragma("unroll")                                                       \
        for (int j = 0; j < 2; ++j) {                                           \
            __builtin_amdgcn_global_load_lds(                                   \
                (const __attribute__((address_space(1))) void*)                 \
                    ((ptr) + ((rowbase) + (hh) * 128 + j * 64 + sj_r) * 1024    \
                           + (tt) * 64 + sj_c),                                 \
                (__attribute__((address_space(3))) void*)                       \
                    (&smem[(slotbase) + j * 4096 + sj_lds]),                    \
                16, 0, 0);                                                      \
        }                                                                       \
    }

#define MFMA16(M0)                                                              \
    __builtin_amdgcn_s_setprio(1);                                              \
    _Pragma("unroll")                                                           \
    for (int mi = 0; mi < 2; ++mi) {                                            \
        _Pragma("unroll")                                                       \
        for (int ni = 0; ni < 4; ++ni) {                                        \
            acc[(M0) + mi][ni] = __builtin_amdgcn_mfma_f32_16x16x32_bf16(       \
                af[mi][0], bf[ni][0], acc[(M0) + mi][ni], 0, 0, 0);             \
            acc[(M0) + mi][ni] = __builtin_amdgcn_mfma_f32_16x16x32_bf16(       \
                af[mi][1], bf[ni][1], acc[(M0) + mi][ni], 0, 0, 0);             \
        }                                                                       \
    }                                                                           \
    __builtin_amdgcn_s_setprio(0);

#define WAIT_LGKM()                                                             \
    asm volatile("s_waitcnt lgkmcnt(0)" ::: "memory");                          \
    __builtin_amdgcn_sched_barrier(0);

__global__ __launch_bounds__(512, 2) void gemm8_k(const short* __restrict__ A,
                                                  const short* __restrict__ Bm,
                                                  short* __restrict__ C) {
    __shared__ short smem[65536];                 // 128 KiB
    const int tid  = threadIdx.x;
    const int lane = tid & 63;
    const int w    = tid >> 6;                    // 0..7
    const int wm   = w >> 2, wn = w & 3;          // 2 x 4 wave grid

    int bid = blockIdx.x;
    bid = (bid & 7) * 72 + (bid >> 3);            // T1 XCD swizzle (576%8==0)
    const int bm = bid / 12, bn = bid % 12;
    const int arow0 = bm * 256, brow0 = bn * 256;

    // staging constants (global source pre-swizzled; LDS dest linear)
    const int sj_r   = w * 8 + (lane >> 3);                  // + j*64 rows
    const int sj_c   = ((lane & 7) ^ (lane >> 3)) * 8;       // k-elems
    const int sj_lds = w * 512;                              // shorts, wave-uniform

    // ds_read constants: phys col (shorts) = (kbyte ^ ((lane&7)<<4)) >> 1
    const int swzc0 = ((((lane >> 4) * 16)) ^ ((lane & 7) << 4)) >> 1;  // ks=0
    const int swzc1 = ((64 + (lane >> 4) * 16) ^ ((lane & 7) << 4)) >> 1; // ks=1
    const int fr = lane & 15;

    f32x4 acc[8][4] = {};
    s16x8 bf[4][2];

    // ---- prologue: B(0), A(0) -> buf0 ; B(1) -> buf1 ----------------------
    STAGE(Bm, brow0, 0, 0, 32768 + 0 * 8192);
    STAGE(Bm, brow0, 0, 1, 32768 + 1 * 8192);
    STAGE(A,  arow0, 0, 0, 0 * 8192);
    STAGE(A,  arow0, 0, 1, 1 * 8192);
    STAGE(Bm, brow0, 1, 0, 32768 + 2 * 8192);
    STAGE(Bm, brow0, 1, 1, 32768 + 3 * 8192);
    asm volatile("s_waitcnt vmcnt(4)" ::: "memory");   // B0,A0 landed; B1 in flight
    __builtin_amdgcn_s_barrier();

    for (int t = 0; t < 16; ++t) {
        const int buf = t & 1;
        const int aslot = (buf * 2 + wm) * 8192;
        const int bslot = 32768 + (buf * 2 + (wn >> 1)) * 8192;
        const int brw = (wn & 1) * 64;
        s16x8 af[2][2];

        // ---- P0: read B-frags(8) + A m0,m1(4); stage A(t+1)h0 -------------
        #pragma unroll
        for (int ni = 0; ni < 4; ++ni) {
            const int r = brw + ni * 16 + fr;
            bf[ni][0] = *(const s16x8*)&smem[bslot + r * 64 + swzc0];
            bf[ni][1] = *(const s16x8*)&smem[bslot + r * 64 + swzc1];
        }
        #pragma unroll
        for (int mi = 0; mi < 2; ++mi) {
            const int r = mi * 16 + fr;
            af[mi][0] = *(const s16x8*)&smem[aslot + r * 64 + swzc0];
            af[mi][1] = *(const s16x8*)&smem[aslot + r * 64 + swzc1];
        }
        if (t + 1 < 16) STAGE(A, arow0, t + 1, 0, ((buf ^ 1) * 2 + 0) * 8192);
        __builtin_amdgcn_s_barrier();
        WAIT_LGKM();
        MFMA16(0);
        __builtin_amdgcn_s_barrier();

        // ---- P1: A m2,m3; stage A(t+1)h1 ----------------------------------
        #pragma unroll
        for (int mi = 0; mi < 2; ++mi) {
            const int r = (mi + 2) * 16 + fr;
            af[mi][0] = *(const s16x8*)&smem[aslot + r * 64 + swzc0];
            af[mi][1] = *(const s16x8*)&smem[aslot + r * 64 + swzc1];
        }
        if (t + 1 < 16) STAGE(A, arow0, t + 1, 1, ((buf ^ 1) * 2 + 1) * 8192);
        __builtin_amdgcn_s_barrier();
        WAIT_LGKM();
        MFMA16(2);
        __builtin_amdgcn_s_barrier();

        // ---- P2: A m4,m5; stage B(t+2)h0 ----------------------------------
        #pragma unroll
        for (int mi = 0; mi < 2; ++mi) {
            const int r = (mi + 4) * 16 + fr;
            af[mi][0] = *(const s16x8*)&smem[aslot + r * 64 + swzc0];
            af[mi][1] = *(const s16x8*)&smem[aslot + r * 64 + swzc1];
        }
        if (t + 2 < 16) STAGE(Bm, brow0, t + 2, 0, 32768 + (buf * 2 + 0) * 8192);
        __builtin_amdgcn_s_barrier();
        WAIT_LGKM();
        MFMA16(4);
        __builtin_amdgcn_s_barrier();

        // ---- P3: A m6,m7; stage B(t+2)h1; boundary vmcnt ------------------
        #pragma unroll
        for (int mi = 0; mi < 2; ++mi) {
            const int r = (mi + 6) * 16 + fr;
            af[mi][0] = *(const s16x8*)&smem[aslot + r * 64 + swzc0];
            af[mi][1] = *(const s16x8*)&smem[aslot + r * 64 + swzc1];
        }
        if (t + 2 < 16) STAGE(Bm, brow0, t + 2, 1, 32768 + (buf * 2 + 1) * 8192);
        __builtin_amdgcn_s_barrier();
        WAIT_LGKM();
        MFMA16(6);
        if (t < 14) { asm volatile("s_waitcnt vmcnt(4)" ::: "memory"); }
        else        { asm volatile("s_waitcnt vmcnt(0)" ::: "memory"); }
        __builtin_amdgcn_s_barrier();
    }

    // ---- epilogue: direct stores (R4: LDS-staged epilogue was neutral) ----
    const int rq = (lane >> 4) * 4;
    #pragma unroll
    for (int mi = 0; mi < 8; ++mi) {
        #pragma unroll
        for (int ni = 0; ni < 4; ++ni) {
            const int r0 = arow0 + wm * 128 + mi * 16 + rq;
            const int c  = brow0 + wn * 64 + ni * 16 + fr;
            #pragma unroll
            for (int r = 0; r < 4; ++r)
                C[(r0 + r) * 3072 + c] = f2bf(acc[mi][ni][r]);
        }
    }
}

// ---- stage 2: theta contraction + bias + residual pad + relu ------------
__global__ __launch_bounds__(256) void stage2_k(const short* __restrict__ xc,
                                                const float* __restrict__ thT,
                                                const float* __restrict__ bias,
                                                const float* __restrict__ x,
                                                float* __restrict__ out) {
    const int blk = blockIdx.x;
    const int tid = threadIdx.x;
    const int nb = blk & 3;
    const int bt = blk >> 2;          // b*12 + t
    const int b  = bt / 12;
    const int t  = bt - b * 12;
    const int n  = nb * 256 + tid;

    float acc[64];
    #pragma unroll
    for (int o = 0; o < 64; ++o) acc[o] = 0.f;

    const int xcbase = (b * 384 + t) * 3072 + n;   // i = 0, k = 0
    for (int i = 0; i < 32; ++i) {
        const int base = xcbase + i * 36864;
        const float v0 = bf2f(xc[base]);
        const float v1 = bf2f(xc[base + 1024]);
        const float v2 = bf2f(xc[base + 2048]);
        const float* t0 = thT + (i * 3) * 64;      // wave-uniform
        #pragma unroll
        for (int o = 0; o < 64; ++o)
            acc[o] = fmaf(t0[o], v0,
                     fmaf(t0[64 + o], v1,
                     fmaf(t0[128 + o], v2, acc[o])));
    }

    const int xrbase = (b * 384 + t) * 1024 + n;   // residual, i = o
    const int obase  = (b * 768 + t) * 1024 + n;
    #pragma unroll
    for (int o = 0; o < 64; ++o) {
        float s = acc[o] + bias[o];
        if (o < 32) s += x[xrbase + o * 12288];
        out[obase + o * 12288] = fmaxf(s, 0.f);
    }
}

extern "C" void kernel_launch(void* const* d_in, const int* in_sizes, int n_in,
                              void* d_out, int out_size, void* d_ws, size_t ws_size,
                              hipStream_t stream) {
    const float* x     = (const float*)d_in[0];
    const float* Lk    = (const float*)d_in[1];
    const float* theta = (const float*)d_in[2];
    const float* bias  = (const float*)d_in[3];
    float* out = (float*)d_out;

    char* ws = (char*)d_ws;
    short* xb  = (short*)(ws);                                  // 25,165,824 B
    short* lb  = (short*)(ws + 25165824);                       //  6,291,456 B
    float* thT = (float*)(ws + 25165824 + 6291456);             //     24,576 B
    short* xc  = (short*)(ws + 25165824 + 6291456 + 24576);     // 75,497,472 B

    hipLaunchKernelGGL(cvt_bf16_k, dim3(6144), dim3(256), 0, stream, x,  xb, 1572864);
    hipLaunchKernelGGL(cvt_bf16_k, dim3(1536), dim3(256), 0, stream, Lk, lb, 393216);
    hipLaunchKernelGGL(tth_k,      dim3(24),   dim3(256), 0, stream, theta, thT);
    hipLaunchKernelGGL(gemm8_k,    dim3(576),  dim3(512), 0, stream, xb, lb, xc);
    hipLaunchKernelGGL(stage2_k,   dim3(1536), dim3(256), 0, stream, xc, thT, bias, x, out);
}

// Round 6
// 234.469 us; speedup vs baseline: 1.4011x; 1.3033x over previous
//
#include <hip/hip_runtime.h>
#include <hip/hip_bf16.h>

// Problem: B=32, c_in=32, T=12, N=1024, ks=3, c_out=64
// R6: FULL FUSION. One GEMM kernel computes out directly:
//   - A rows regrouped: M-tile = 8 (b,t) x 32 i  (per-lane source rows)
//   - B rows ordered r_b = n*3+k  -> N-tile 192 = 64 n x 3 k
//   - 8-phase schedule (proven R5), 48 MFMA/K-step/wave, vmcnt(3) boundary
//   - epilogue: acc -> LDS P^T[G][n][ik] -> per-wave theta-MFMA (64x64x96)
//     + bias + residual(pad) + relu -> out.  No xc intermediate, no stage2.

typedef __attribute__((ext_vector_type(8))) short s16x8;
typedef __attribute__((ext_vector_type(4))) float f32x4;
typedef __attribute__((ext_vector_type(4))) float fvec4;

__device__ __forceinline__ short f2bf(float f) {
    union { float f; unsigned u; } v; v.f = f;
    unsigned r = v.u + 0x7fffu + ((v.u >> 16) & 1u);   // RNE
    return (short)(r >> 16);
}

// ---- fused prep: x->bf16, Lk->bf16 (n*3+k)-row-ordered, theta->bf16 [o][96]
#define U1 1572864   // x units (8 f32 each)
#define U2 393216    // lbT units (8 elems each)
#define U3 6144      // theta elems
__global__ __launch_bounds__(256) void prep_k(const float* __restrict__ x,
                                              const float* __restrict__ Lk,
                                              const float* __restrict__ th,
                                              short* __restrict__ xb,
                                              short* __restrict__ lbT,
                                              short* __restrict__ thb) {
    int gid = blockIdx.x * 256 + threadIdx.x;
    if (gid < U1) {
        const fvec4* s4 = (const fvec4*)x;
        fvec4 a = s4[2 * gid], b = s4[2 * gid + 1];
        s16x8 o;
        o[0]=f2bf(a[0]); o[1]=f2bf(a[1]); o[2]=f2bf(a[2]); o[3]=f2bf(a[3]);
        o[4]=f2bf(b[0]); o[5]=f2bf(b[1]); o[6]=f2bf(b[2]); o[7]=f2bf(b[3]);
        ((s16x8*)xb)[gid] = o;
    } else if (gid < U1 + U2) {
        int u = gid - U1;
        int row = u >> 7, m8 = u & 127;       // row = n*3+k
        int n = row / 3, k = row - n * 3;
        const fvec4* s4 = (const fvec4*)(Lk + (k << 20) + n * 1024 + m8 * 8);
        fvec4 a = s4[0], b = s4[1];
        s16x8 o;
        o[0]=f2bf(a[0]); o[1]=f2bf(a[1]); o[2]=f2bf(a[2]); o[3]=f2bf(a[3]);
        o[4]=f2bf(b[0]); o[5]=f2bf(b[1]); o[6]=f2bf(b[2]); o[7]=f2bf(b[3]);
        ((s16x8*)lbT)[row * 128 + m8] = o;
    } else if (gid < U1 + U2 + U3) {
        int e = gid - U1 - U2;                // theta (i,o,k): e = i*192+o*3+k
        int i = e / 192, rem = e - i * 192;
        int o = rem / 3, k = rem - o * 3;
        thb[o * 96 + i * 3 + k] = f2bf(th[e]);
    }
}

// ===== fused 8-phase GEMM + theta epilogue ===============================
// LDS: A dbuf 2x(256x64)=64KB @0 ; B dbuf 2x(192x64)=48KB @32768 shorts.
// T2 swizzle byte ^= ((row&7)<<4) via pre-swizzled global src + swz ds_read.
#define STAGE_A(kstep, j, bufb)                                                 \
    __builtin_amdgcn_global_load_lds(                                           \
        (const __attribute__((address_space(1))) void*)                         \
            (A + a_srcoff[j] + (kstep) * 64),                                   \
        (__attribute__((address_space(3))) void*)                               \
            (&smem[(bufb) * 16384 + (j) * 4096 + w * 512]), 16, 0, 0);

#define STAGE_B(kstep, j, bufb)                                                 \
    __builtin_amdgcn_global_load_lds(                                           \
        (const __attribute__((address_space(1))) void*)                         \
            (Bm + b_srcoff[j] + (kstep) * 64),                                  \
        (__attribute__((address_space(3))) void*)                               \
            (&smem[32768 + (bufb) * 12288 + (j) * 4096 + w * 512]), 16, 0, 0);

#define MFMA12(M0)                                                              \
    __builtin_amdgcn_s_setprio(1);                                              \
    _Pragma("unroll")                                                           \
    for (int mi = 0; mi < 2; ++mi) {                                            \
        _Pragma("unroll")                                                       \
        for (int ni = 0; ni < 3; ++ni) {                                        \
            acc[(M0) + mi][ni] = __builtin_amdgcn_mfma_f32_16x16x32_bf16(       \
                af[mi][0], bfm[ni][0], acc[(M0) + mi][ni], 0, 0, 0);            \
            acc[(M0) + mi][ni] = __builtin_amdgcn_mfma_f32_16x16x32_bf16(       \
                af[mi][1], bfm[ni][1], acc[(M0) + mi][ni], 0, 0, 0);            \
        }                                                                       \
    }                                                                           \
    __builtin_amdgcn_s_setprio(0);

#define WAIT_LGKM()                                                             \
    asm volatile("s_waitcnt lgkmcnt(0)" ::: "memory");                          \
    __builtin_amdgcn_sched_barrier(0);

__global__ __launch_bounds__(512, 2) void fused_k(const short* __restrict__ A,
                                                  const short* __restrict__ Bm,
                                                  const short* __restrict__ thb,
                                                  const float* __restrict__ bias,
                                                  const float* __restrict__ xres,
                                                  float* __restrict__ out) {
    __shared__ short smem[57344];                 // 112 KiB
    const int tid  = threadIdx.x;
    const int lane = tid & 63;
    const int w    = tid >> 6;                    // 0..7
    const int wm   = w >> 2, wn = w & 3;          // 2 x 4 wave grid

    int bid = blockIdx.x;
    bid = (bid & 7) * 96 + (bid >> 3);            // T1 XCD swizzle (768%8==0)
    const int bm = bid >> 4, bn = bid & 15;       // 48 x 16 tiles
    const int g0 = bm * 8;                        // first (b,t) group

    // staging geometry (source pre-swizzled, LDS dest linear)
    const int srow8 = w * 8 + (lane >> 3);        // 0..63 within a quarter
    const int sj_c  = ((lane & 7) ^ (lane >> 3)) * 8;

    int a_srcoff[4];
    #pragma unroll
    for (int j = 0; j < 4; ++j) {
        const int q = j * 64 + srow8;             // local M row 0..255
        const int G = q >> 5, i = q & 31;
        const int g = g0 + G;
        const int b = g / 12, t_ = g - b * 12;
        a_srcoff[j] = (b * 384 + i * 12 + t_) * 1024 + sj_c;
    }
    int b_srcoff[3];
    #pragma unroll
    for (int j = 0; j < 3; ++j)
        b_srcoff[j] = (bn * 192 + j * 64 + srow8) * 1024 + sj_c;

    // swizzled ds_read col offsets (shorts)
    const int swzc0 = ((((lane >> 4) * 16)) ^ ((lane & 7) << 4)) >> 1;
    const int swzc1 = ((64 + (lane >> 4) * 16) ^ ((lane & 7) << 4)) >> 1;
    const int fr = lane & 15;

    f32x4 acc[8][3] = {};
    s16x8 bfm[3][2];

    // ---- prologue: A(0) 4q, B(0) 3q, B(1) 3q --------------------------------
    STAGE_A(0, 0, 0) STAGE_A(0, 1, 0) STAGE_A(0, 2, 0) STAGE_A(0, 3, 0)
    STAGE_B(0, 0, 0) STAGE_B(0, 1, 0) STAGE_B(0, 2, 0)
    STAGE_B(1, 0, 1) STAGE_B(1, 1, 1) STAGE_B(1, 2, 1)
    asm volatile("s_waitcnt vmcnt(3)" ::: "memory");   // A0,B0 landed; B1 flying
    __builtin_amdgcn_s_barrier();

    for (int t = 0; t < 16; ++t) {
        const int buf = t & 1;
        const int abase = buf * 16384;
        const int bbase = 32768 + buf * 12288;
        s16x8 af[2][2];

        // P0: B frags (6) + A m0,m1; stage A(t+1) q0,q1
        #pragma unroll
        for (int ni = 0; ni < 3; ++ni) {
            const int r = wn * 48 + ni * 16 + fr;
            bfm[ni][0] = *(const s16x8*)&smem[bbase + r * 64 + swzc0];
            bfm[ni][1] = *(const s16x8*)&smem[bbase + r * 64 + swzc1];
        }
        #pragma unroll
        for (int mi = 0; mi < 2; ++mi) {
            const int r = wm * 128 + mi * 16 + fr;
            af[mi][0] = *(const s16x8*)&smem[abase + r * 64 + swzc0];
            af[mi][1] = *(const s16x8*)&smem[abase + r * 64 + swzc1];
        }
        if (t + 1 < 16) { STAGE_A(t + 1, 0, buf ^ 1) STAGE_A(t + 1, 1, buf ^ 1) }
        __builtin_amdgcn_s_barrier();
        WAIT_LGKM();
        MFMA12(0);
        __builtin_amdgcn_s_barrier();

        // P1: A m2,m3; stage A(t+1) q2,q3
        #pragma unroll
        for (int mi = 0; mi < 2; ++mi) {
            const int r = wm * 128 + (mi + 2) * 16 + fr;
            af[mi][0] = *(const s16x8*)&smem[abase + r * 64 + swzc0];
            af[mi][1] = *(const s16x8*)&smem[abase + r * 64 + swzc1];
        }
        if (t + 1 < 16) { STAGE_A(t + 1, 2, buf ^ 1) STAGE_A(t + 1, 3, buf ^ 1) }
        __builtin_amdgcn_s_barrier();
        WAIT_LGKM();
        MFMA12(2);
        __builtin_amdgcn_s_barrier();

        // P2: A m4,m5; stage B(t+2) q0,q1
        #pragma unroll
        for (int mi = 0; mi < 2; ++mi) {
            const int r = wm * 128 + (mi + 4) * 16 + fr;
            af[mi][0] = *(const s16x8*)&smem[abase + r * 64 + swzc0];
            af[mi][1] = *(const s16x8*)&smem[abase + r * 64 + swzc1];
        }
        if (t + 2 < 16) { STAGE_B(t + 2, 0, buf) STAGE_B(t + 2, 1, buf) }
        __builtin_amdgcn_s_barrier();
        WAIT_LGKM();
        MFMA12(4);
        __builtin_amdgcn_s_barrier();

        // P3: A m6,m7; stage B(t+2) q2; boundary vmcnt
        #pragma unroll
        for (int mi = 0; mi < 2; ++mi) {
            const int r = wm * 128 + (mi + 6) * 16 + fr;
            af[mi][0] = *(const s16x8*)&smem[abase + r * 64 + swzc0];
            af[mi][1] = *(const s16x8*)&smem[abase + r * 64 + swzc1];
        }
        if (t + 2 < 16) { STAGE_B(t + 2, 2, buf) }
        __builtin_amdgcn_s_barrier();
        WAIT_LGKM();
        MFMA12(6);
        if (t < 14) { asm volatile("s_waitcnt vmcnt(3)" ::: "memory"); }
        else        { asm volatile("s_waitcnt vmcnt(0)" ::: "memory"); }
        __builtin_amdgcn_s_barrier();
    }

    // ---- epilogue 1: acc -> LDS P^T[G][n_l][i*3+k], row stride 104 shorts ---
    const int rq = (lane >> 4) * 4;
    #pragma unroll
    for (int mi = 0; mi < 8; ++mi) {
        const int G = wm * 4 + (mi >> 1);
        const int ib = (mi & 1) * 16 + rq;
        #pragma unroll
        for (int ni = 0; ni < 3; ++ni) {
            const int c  = wn * 48 + ni * 16 + fr;   // = n_l*3 + k
            const int nl = c / 3, kk = c - nl * 3;
            const int base = G * 6656 + nl * 104 + kk;
            #pragma unroll
            for (int r = 0; r < 4; ++r)
                smem[base + (ib + r) * 3] = f2bf(acc[mi][ni][r]);
        }
    }
    __syncthreads();

    // ---- epilogue 2: per-wave theta-MFMA (64o x 64n, K=96) + writeout -------
    const int g  = g0 + w;
    const int b  = g / 12, t_ = g - b * 12;
    const int rq8 = (lane >> 4) * 8;
    s16x8 ta[4][3];
    #pragma unroll
    for (int oi = 0; oi < 4; ++oi)
        #pragma unroll
        for (int ks = 0; ks < 3; ++ks)
            ta[oi][ks] = *(const s16x8*)&thb[(oi * 16 + fr) * 96 + ks * 32 + rq8];

    f32x4 a2[4][4] = {};
    #pragma unroll
    for (int nj = 0; nj < 4; ++nj) {
        s16x8 pb[3];
        #pragma unroll
        for (int ks = 0; ks < 3; ++ks)
            pb[ks] = *(const s16x8*)&smem[w * 6656 + (nj * 16 + fr) * 104 + ks * 32 + rq8];
        #pragma unroll
        for (int oi = 0; oi < 4; ++oi)
            #pragma unroll
            for (int ks = 0; ks < 3; ++ks)
                a2[oi][nj] = __builtin_amdgcn_mfma_f32_16x16x32_bf16(
                    ta[oi][ks], pb[ks], a2[oi][nj], 0, 0, 0);
    }

    const int n0 = bn * 64;
    #pragma unroll
    for (int oi = 0; oi < 4; ++oi) {
        #pragma unroll
        for (int nj = 0; nj < 4; ++nj) {
            const int nl = n0 + nj * 16 + fr;
            #pragma unroll
            for (int r = 0; r < 4; ++r) {
                const int o = oi * 16 + rq + r;
                float v = a2[oi][nj][r] + bias[o];
                if (o < 32) v += xres[(b * 384 + o * 12 + t_) * 1024 + nl];
                out[((b * 64 + o) * 12 + t_) * 1024 + nl] = fmaxf(v, 0.f);
            }
        }
    }
}

extern "C" void kernel_launch(void* const* d_in, const int* in_sizes, int n_in,
                              void* d_out, int out_size, void* d_ws, size_t ws_size,
                              hipStream_t stream) {
    const float* x     = (const float*)d_in[0];
    const float* Lk    = (const float*)d_in[1];
    const float* theta = (const float*)d_in[2];
    const float* bias  = (const float*)d_in[3];
    float* out = (float*)d_out;

    char* ws = (char*)d_ws;
    short* xb  = (short*)(ws);                      // 25,165,824 B
    short* lbT = (short*)(ws + 25165824);           //  6,291,456 B
    short* thb = (short*)(ws + 31457280);           //     12,288 B

    hipLaunchKernelGGL(prep_k,  dim3(7704), dim3(256), 0, stream,
                       x, Lk, theta, xb, lbT, thb);
    hipLaunchKernelGGL(fused_k, dim3(768),  dim3(512), 0, stream,
                       xb, lbT, thb, bias, x, out);
}

// Round 8
// 228.406 us; speedup vs baseline: 1.4382x; 1.0265x over previous
//
#include <hip/hip_runtime.h>
#include <hip/hip_bf16.h>

// Problem: B=32, c_in=32, T=12, N=1024, ks=3, c_out=64
// R7: R6 fused structure +
//   (a) 3-slot A ring: A staged 2 K-steps ahead (was 1) -> boundary vmcnt(7)
//       covers HBM latency (~900cyc) instead of ~2.5 phases.
//   (b) residual read from bf16 xb (A) instead of fp32 x: -25 MB FETCH.

typedef __attribute__((ext_vector_type(8))) short s16x8;
typedef __attribute__((ext_vector_type(4))) float f32x4;
typedef __attribute__((ext_vector_type(4))) float fvec4;

__device__ __forceinline__ short f2bf(float f) {
    union { float f; unsigned u; } v; v.f = f;
    unsigned r = v.u + 0x7fffu + ((v.u >> 16) & 1u);   // RNE
    return (short)(r >> 16);
}
__device__ __forceinline__ float bf2f(short h) {
    union { unsigned u; float f; } v; v.u = ((unsigned)(unsigned short)h) << 16;
    return v.f;
}

// ---- fused prep: x->bf16, Lk->bf16 (n*3+k)-row-ordered, theta->bf16 [o][96]
#define U1 1572864   // x units (8 f32 each)
#define U2 393216    // lbT units (8 elems each)
#define U3 6144      // theta elems
__global__ __launch_bounds__(256) void prep_k(const float* __restrict__ x,
                                              const float* __restrict__ Lk,
                                              const float* __restrict__ th,
                                              short* __restrict__ xb,
                                              short* __restrict__ lbT,
                                              short* __restrict__ thb) {
    int gid = blockIdx.x * 256 + threadIdx.x;
    if (gid < U1) {
        const fvec4* s4 = (const fvec4*)x;
        fvec4 a = s4[2 * gid], b = s4[2 * gid + 1];
        s16x8 o;
        o[0]=f2bf(a[0]); o[1]=f2bf(a[1]); o[2]=f2bf(a[2]); o[3]=f2bf(a[3]);
        o[4]=f2bf(b[0]); o[5]=f2bf(b[1]); o[6]=f2bf(b[2]); o[7]=f2bf(b[3]);
        ((s16x8*)xb)[gid] = o;
    } else if (gid < U1 + U2) {
        int u = gid - U1;
        int row = u >> 7, m8 = u & 127;       // row = n*3+k
        int n = row / 3, k = row - n * 3;
        const fvec4* s4 = (const fvec4*)(Lk + (k << 20) + n * 1024 + m8 * 8);
        fvec4 a = s4[0], b = s4[1];
        s16x8 o;
        o[0]=f2bf(a[0]); o[1]=f2bf(a[1]); o[2]=f2bf(a[2]); o[3]=f2bf(a[3]);
        o[4]=f2bf(b[0]); o[5]=f2bf(b[1]); o[6]=f2bf(b[2]); o[7]=f2bf(b[3]);
        ((s16x8*)lbT)[row * 128 + m8] = o;
    } else if (gid < U1 + U2 + U3) {
        int e = gid - U1 - U2;                // theta (i,o,k): e = i*192+o*3+k
        int i = e / 192, rem = e - i * 192;
        int o = rem / 3, k = rem - o * 3;
        thb[o * 96 + i * 3 + k] = f2bf(th[e]);
    }
}

// ===== fused 8-phase GEMM + theta epilogue ===============================
// LDS (shorts): A ring 3 x 8192(=256x64) @0,16384,32768 ; B dbuf 2 x 12288
// (=192x64) @49152, 61440.  Total 73728 shorts = 144 KiB.
// T2 swizzle byte ^= ((row&7)<<4) via pre-swizzled global src + swz ds_read.
#define STAGE_A(kstep, j, ldsb)                                                 \
    __builtin_amdgcn_global_load_lds(                                           \
        (const __attribute__((address_space(1))) void*)                         \
            (A + a_srcoff[j] + (kstep) * 64),                                   \
        (__attribute__((address_space(3))) void*)                               \
            (&smem[(ldsb) + (j) * 4096 + w * 512]), 16, 0, 0);

#define STAGE_B(kstep, j, ldsb)                                                 \
    __builtin_amdgcn_global_load_lds(                                           \
        (const __attribute__((address_space(1))) void*)                         \
            (Bm + b_srcoff[j] + (kstep) * 64),                                  \
        (__attribute__((address_space(3))) void*)                               \
            (&smem[(ldsb) + (j) * 4096 + w * 512]), 16, 0, 0);

#define MFMA12(M0)                                                              \
    __builtin_amdgcn_s_setprio(1);                                              \
    _Pragma("unroll")                                                           \
    for (int mi = 0; mi < 2; ++mi) {                                            \
        _Pragma("unroll")                                                       \
        for (int ni = 0; ni < 3; ++ni) {                                        \
            acc[(M0) + mi][ni] = __builtin_amdgcn_mfma_f32_16x16x32_bf16(       \
                af[mi][0], bfm[ni][0], acc[(M0) + mi][ni], 0, 0, 0);            \
            acc[(M0) + mi][ni] = __builtin_amdgcn_mfma_f32_16x16x32_bf16(       \
                af[mi][1], bfm[ni][1], acc[(M0) + mi][ni], 0, 0, 0);            \
        }                                                                       \
    }                                                                           \
    __builtin_amdgcn_s_setprio(0);

#define WAIT_LGKM()                                                             \
    asm volatile("s_waitcnt lgkmcnt(0)" ::: "memory");                          \
    __builtin_amdgcn_sched_barrier(0);

__global__ __launch_bounds__(512, 2) void fused_k(const short* __restrict__ A,
                                                  const short* __restrict__ Bm,
                                                  const short* __restrict__ thb,
                                                  const float* __restrict__ bias,
                                                  float* __restrict__ out) {
    __shared__ short smem[73728];                 // 144 KiB
    const int tid  = threadIdx.x;
    const int lane = tid & 63;
    const int w    = tid >> 6;                    // 0..7
    const int wm   = w >> 2, wn = w & 3;          // 2 x 4 wave grid

    int bid = blockIdx.x;
    bid = (bid & 7) * 96 + (bid >> 3);            // T1 XCD swizzle (768%8==0)
    const int bm = bid >> 4, bn = bid & 15;       // 48 x 16 tiles
    const int g0 = bm * 8;                        // first (b,t) group

    // staging geometry (source pre-swizzled, LDS dest linear)
    const int srow8 = w * 8 + (lane >> 3);        // 0..63 within a quarter
    const int sj_c  = ((lane & 7) ^ (lane >> 3)) * 8;

    int a_srcoff[4];
    #pragma unroll
    for (int j = 0; j < 4; ++j) {
        const int q = j * 64 + srow8;             // local M row 0..255
        const int G = q >> 5, i = q & 31;
        const int g = g0 + G;
        const int b = g / 12, t_ = g - b * 12;
        a_srcoff[j] = (b * 384 + i * 12 + t_) * 1024 + sj_c;
    }
    int b_srcoff[3];
    #pragma unroll
    for (int j = 0; j < 3; ++j)
        b_srcoff[j] = (bn * 192 + j * 64 + srow8) * 1024 + sj_c;

    // swizzled ds_read col offsets (shorts)
    const int swzc0 = ((((lane >> 4) * 16)) ^ ((lane & 7) << 4)) >> 1;
    const int swzc1 = ((64 + (lane >> 4) * 16) ^ ((lane & 7) << 4)) >> 1;
    const int fr = lane & 15;

    f32x4 acc[8][3] = {};
    s16x8 bfm[3][2];

    // ---- prologue: A(0)->s0, B(0)->b0, A(1)->s1, B(1)->b1 ------------------
    STAGE_A(0, 0, 0)     STAGE_A(0, 1, 0)     STAGE_A(0, 2, 0)     STAGE_A(0, 3, 0)
    STAGE_B(0, 0, 49152) STAGE_B(0, 1, 49152) STAGE_B(0, 2, 49152)
    STAGE_A(1, 0, 16384) STAGE_A(1, 1, 16384) STAGE_A(1, 2, 16384) STAGE_A(1, 3, 16384)
    STAGE_B(1, 0, 61440) STAGE_B(1, 1, 61440) STAGE_B(1, 2, 61440)
    asm volatile("s_waitcnt vmcnt(7)" ::: "memory");   // A0,B0 landed; A1,B1 flying
    __builtin_amdgcn_s_barrier();

    int rs = 0, ss = 2;                           // read slot, stage slot (=rs+2 mod 3)
    for (int t = 0; t < 16; ++t) {
        const int abase = rs * 16384;
        const int astg  = ss * 16384;
        const int bbase = 49152 + (t & 1) * 12288;   // read & stage slot (WAR-safe)
        s16x8 af[2][2];

        // P0: B frags (6) + A m0,m1; stage A(t+2) q0,q1
        #pragma unroll
        for (int ni = 0; ni < 3; ++ni) {
            const int r = wn * 48 + ni * 16 + fr;
            bfm[ni][0] = *(const s16x8*)&smem[bbase + r * 64 + swzc0];
            bfm[ni][1] = *(const s16x8*)&smem[bbase + r * 64 + swzc1];
        }
        #pragma unroll
        for (int mi = 0; mi < 2; ++mi) {
            const int r = wm * 128 + mi * 16 + fr;
            af[mi][0] = *(const s16x8*)&smem[abase + r * 64 + swzc0];
            af[mi][1] = *(const s16x8*)&smem[abase + r * 64 + swzc1];
        }
        if (t < 14) { STAGE_A(t + 2, 0, astg) STAGE_A(t + 2, 1, astg) }
        __builtin_amdgcn_s_barrier();
        WAIT_LGKM();
        MFMA12(0);
        __builtin_amdgcn_s_barrier();

        // P1: A m2,m3; stage A(t+2) q2,q3
        #pragma unroll
        for (int mi = 0; mi < 2; ++mi) {
            const int r = wm * 128 + (mi + 2) * 16 + fr;
            af[mi][0] = *(const s16x8*)&smem[abase + r * 64 + swzc0];
            af[mi][1] = *(const s16x8*)&smem[abase + r * 64 + swzc1];
        }
        if (t < 14) { STAGE_A(t + 2, 2, astg) STAGE_A(t + 2, 3, astg) }
        __builtin_amdgcn_s_barrier();
        WAIT_LGKM();
        MFMA12(2);
        __builtin_amdgcn_s_barrier();

        // P2: A m4,m5; stage B(t+2) q0,q1
        #pragma unroll
        for (int mi = 0; mi < 2; ++mi) {
            const int r = wm * 128 + (mi + 4) * 16 + fr;
            af[mi][0] = *(const s16x8*)&smem[abase + r * 64 + swzc0];
            af[mi][1] = *(const s16x8*)&smem[abase + r * 64 + swzc1];
        }
        if (t < 14) { STAGE_B(t + 2, 0, bbase) STAGE_B(t + 2, 1, bbase) }
        __builtin_amdgcn_s_barrier();
        WAIT_LGKM();
        MFMA12(4);
        __builtin_amdgcn_s_barrier();

        // P3: A m6,m7; stage B(t+2) q2; boundary vmcnt
        #pragma unroll
        for (int mi = 0; mi < 2; ++mi) {
            const int r = wm * 128 + (mi + 6) * 16 + fr;
            af[mi][0] = *(const s16x8*)&smem[abase + r * 64 + swzc0];
            af[mi][1] = *(const s16x8*)&smem[abase + r * 64 + swzc1];
        }
        if (t < 14) { STAGE_B(t + 2, 2, bbase) }
        __builtin_amdgcn_s_barrier();
        WAIT_LGKM();
        MFMA12(6);
        if (t < 14) { asm volatile("s_waitcnt vmcnt(7)" ::: "memory"); }
        else        { asm volatile("s_waitcnt vmcnt(0)" ::: "memory"); }
        __builtin_amdgcn_s_barrier();
        rs = (rs == 2) ? 0 : rs + 1;
        ss = (ss == 2) ? 0 : ss + 1;
    }

    // ---- epilogue 1: acc -> LDS P^T[G][n_l][i*3+k], row stride 104 shorts ---
    const int rq = (lane >> 4) * 4;
    #pragma unroll
    for (int mi = 0; mi < 8; ++mi) {
        const int G = wm * 4 + (mi >> 1);
        const int ib = (mi & 1) * 16 + rq;
        #pragma unroll
        for (int ni = 0; ni < 3; ++ni) {
            const int c  = wn * 48 + ni * 16 + fr;   // = n_l*3 + k
            const int nl = c / 3, kk = c - nl * 3;
            const int base = G * 6656 + nl * 104 + kk;
            #pragma unroll
            for (int r = 0; r < 4; ++r)
                smem[base + (ib + r) * 3] = f2bf(acc[mi][ni][r]);
        }
    }
    __syncthreads();

    // ---- epilogue 2: per-wave theta-MFMA (64o x 64n, K=96) + writeout -------
    const int g  = g0 + w;
    const int b  = g / 12, t_ = g - b * 12;
    const int rq8 = (lane >> 4) * 8;
    s16x8 ta[4][3];
    #pragma unroll
    for (int oi = 0; oi < 4; ++oi)
        #pragma unroll
        for (int ks = 0; ks < 3; ++ks)
            ta[oi][ks] = *(const s16x8*)&thb[(oi * 16 + fr) * 96 + ks * 32 + rq8];

    f32x4 a2[4][4] = {};
    #pragma unroll
    for (int nj = 0; nj < 4; ++nj) {
        s16x8 pb[3];
        #pragma unroll
        for (int ks = 0; ks < 3; ++ks)
            pb[ks] = *(const s16x8*)&smem[w * 6656 + (nj * 16 + fr) * 104 + ks * 32 + rq8];
        #pragma unroll
        for (int oi = 0; oi < 4; ++oi)
            #pragma unroll
            for (int ks = 0; ks < 3; ++ks)
                a2[oi][nj] = __builtin_amdgcn_mfma_f32_16x16x32_bf16(
                    ta[oi][ks], pb[ks], a2[oi][nj], 0, 0, 0);
    }

    const int n0 = bn * 64;
    #pragma unroll
    for (int oi = 0; oi < 4; ++oi) {
        #pragma unroll
        for (int nj = 0; nj < 4; ++nj) {
            const int nl = n0 + nj * 16 + fr;
            #pragma unroll
            for (int r = 0; r < 4; ++r) {
                const int o = oi * 16 + rq + r;
                float v = a2[oi][nj][r] + bias[o];
                if (o < 32) v += bf2f(A[(b * 384 + o * 12 + t_) * 1024 + nl]);
                out[((b * 64 + o) * 12 + t_) * 1024 + nl] = fmaxf(v, 0.f);
            }
        }
    }
}

extern "C" void kernel_launch(void* const* d_in, const int* in_sizes, int n_in,
                              void* d_out, int out_size, void* d_ws, size_t ws_size,
                              hipStream_t stream) {
    const float* x     = (const float*)d_in[0];
    const float* Lk    = (const float*)d_in[1];
    const float* theta = (const float*)d_in[2];
    const float* bias  = (const float*)d_in[3];
    float* out = (float*)d_out;

    char* ws = (char*)d_ws;
    short* xb  = (short*)(ws);                      // 25,165,824 B
    short* lbT = (short*)(ws + 25165824);           //  6,291,456 B
    short* thb = (short*)(ws + 31457280);           //     12,288 B

    hipLaunchKernelGGL(prep_k,  dim3(7704), dim3(256), 0, stream,
                       x, Lk, theta, xb, lbT, thb);
    hipLaunchKernelGGL(fused_k, dim3(768),  dim3(512), 0, stream,
                       xb, lbT, thb, bias, out);
}